// Round 1
// baseline (400.497 us; speedup 1.0000x reference)
//
#include <hip/hip_runtime.h>

#define N_NODES 10000
#define N_EDGES 320000
#define HIDDEN 16
#define MSG 64
#define EDGE_FEAT 32
#define BE 64      // edges per block
#define KT 64      // K-tile (= 4 edge-feature rows x 16 hidden)

// out[n,m] = sum over edges e with tgt[e]==n of (Z[e] @ Wr)[m] + bias-term
// Z[e, f*16+h] = ef[e,f] * hidden[src[e],h];  Wr[f*16+h, m] = W[f, m*16+h]
__global__ __launch_bounds__(256, 3) void msg_kernel(
    const float* __restrict__ ef,      // [E,32]
    const int*   __restrict__ src,     // [E]
    const int*   __restrict__ tgt,     // [E]
    const float* __restrict__ hidden,  // [N,16]
    const float* __restrict__ W,       // [32,1024]
    const float* __restrict__ bias,    // [1024]
    float*       __restrict__ out)     // [N,64]
{
    __shared__ float neigh_s[BE][17];   // gathered hidden rows
    __shared__ float ef_s[BE][33];      // edge features
    __shared__ float Zs[KT][68];        // Z tile, [k][e], padded for b128 align
    __shared__ float Ws[KT][68];        // Wr tile, [k][m]

    const int tid = threadIdx.x;
    const int e0  = blockIdx.x * BE;
    const int tx  = tid & 15;          // m-quad index  (m = tx*4 + j)
    const int ty  = tid >> 4;          // edge-quad index (e = ty*4 + i)

    // ---- gather neighbor hidden states: thread t -> edge t>>2, 4 floats ----
    {
        const int e  = tid >> 2;
        const int h4 = (tid & 3) * 4;
        const int s  = src[e0 + e];
        const float4 v = *(const float4*)(hidden + (size_t)s * HIDDEN + h4);
        neigh_s[e][h4 + 0] = v.x;
        neigh_s[e][h4 + 1] = v.y;
        neigh_s[e][h4 + 2] = v.z;
        neigh_s[e][h4 + 3] = v.w;
    }
    // ---- load edge features: thread t -> edge t>>2, 8 floats ----
    {
        const int e  = tid >> 2;
        const int f8 = (tid & 3) * 8;
        const float* p = ef + (size_t)(e0 + e) * EDGE_FEAT + f8;
        const float4 v0 = *(const float4*)(p);
        const float4 v1 = *(const float4*)(p + 4);
        ef_s[e][f8 + 0] = v0.x; ef_s[e][f8 + 1] = v0.y;
        ef_s[e][f8 + 2] = v0.z; ef_s[e][f8 + 3] = v0.w;
        ef_s[e][f8 + 4] = v1.x; ef_s[e][f8 + 5] = v1.y;
        ef_s[e][f8 + 6] = v1.z; ef_s[e][f8 + 7] = v1.w;
    }
    __syncthreads();

    float acc[4][4] = {};

    #pragma unroll 1
    for (int kt = 0; kt < 8; ++kt) {
        const int f0 = kt * 4;

        // ---- stage Wr tile: Ws[(f-f0)*16+h][m] = W[f, m*16+h], coalesced global ----
        #pragma unroll
        for (int i = 0; i < 16; ++i) {
            const int idx = tid + i * 256;       // 0..4095
            const int fl  = idx >> 10;           // 0..3
            const int c   = idx & 1023;          // m*16+h
            const int m   = c >> 4;
            const int h   = c & 15;
            Ws[fl * 16 + h][m] = W[(size_t)(f0 + fl) * 1024 + c];
        }
        // ---- stage Z tile: Zs[k][e] = ef[e, f0+k/16] * neigh[e, k%16] ----
        #pragma unroll
        for (int i = 0; i < 16; ++i) {
            const int idx = tid + i * 256;       // 0..4095
            const int k   = idx >> 6;            // 0..63
            const int e   = idx & 63;
            Zs[k][e] = ef_s[e][f0 + (k >> 4)] * neigh_s[e][k & 15];
        }
        __syncthreads();

        // ---- inner GEMM: 16 FMA per k per thread ----
        #pragma unroll
        for (int k = 0; k < KT; ++k) {
            const float4 av = *(const float4*)&Zs[k][ty * 4];
            const float4 bv = *(const float4*)&Ws[k][tx * 4];
            const float a[4] = {av.x, av.y, av.z, av.w};
            const float b[4] = {bv.x, bv.y, bv.z, bv.w};
            #pragma unroll
            for (int i = 0; i < 4; ++i)
                #pragma unroll
                for (int j = 0; j < 4; ++j)
                    acc[i][j] += a[i] * b[j];
        }
        __syncthreads();
    }

    // ---- bias term + atomic scatter into out ----
    #pragma unroll
    for (int i = 0; i < 4; ++i) {
        const int el = ty * 4 + i;
        const int t  = tgt[e0 + el];
        #pragma unroll
        for (int j = 0; j < 4; ++j) {
            const int m = tx * 4 + j;
            float bv = 0.f;
            #pragma unroll
            for (int h = 0; h < HIDDEN; ++h)
                bv += bias[m * 16 + h] * neigh_s[el][h];
            atomicAdd(out + (size_t)t * MSG + m, acc[i][j] + bv);
        }
    }
}

extern "C" void kernel_launch(void* const* d_in, const int* in_sizes, int n_in,
                              void* d_out, int out_size, void* d_ws, size_t ws_size,
                              hipStream_t stream) {
    // inputs: 0 node_features (unused), 1 edge_features, 2 edge_sources,
    //         3 edge_targets, 4 hidden, 5 initial (unused), 6 W, 7 b
    const float* ef     = (const float*)d_in[1];
    const int*   src    = (const int*)d_in[2];
    const int*   tgt    = (const int*)d_in[3];
    const float* hidden = (const float*)d_in[4];
    const float* W      = (const float*)d_in[6];
    const float* bias   = (const float*)d_in[7];
    float* out = (float*)d_out;

    // harness poisons d_out with 0xAA and does not re-poison between replays:
    // zero it every call, then accumulate with atomics.
    hipMemsetAsync(out, 0, (size_t)out_size * sizeof(float), stream);

    const int nblocks = N_EDGES / BE;  // 5000
    msg_kernel<<<nblocks, 256, 0, stream>>>(ef, src, tgt, hidden, W, bias, out);
}

// Round 2
// 95.492 us; speedup vs baseline: 4.1940x; 4.1940x over previous
//
#include <hip/hip_runtime.h>
#include <hip/hip_bf16.h>

#define N_NODES 10000
#define N_EDGES 320000
#define HIDDEN 16
#define MSG 64
#define EDGE_FEAT 32
#define KTOT 544          // 512 (ef x hidden) + 16 (bias row) + 16 (zero pad) = 17 k-steps of 32
#define KSTEPS 17

typedef __attribute__((ext_vector_type(8))) short bf16x8;   // 8 x bf16 (4 VGPRs)
typedef __attribute__((ext_vector_type(4))) float f32x4;    // MFMA accumulator

// ---------------------------------------------------------------------------
// Prep: pack Wr (+bias extension) into per-lane MFMA B-fragment order.
// Wr[k][n] = W[k>>4][n*16 + (k&15)] for k<512; = bias[n*16+(k-512)] for k<528; 0 else.
// B-frag layout for mfma_f32_16x16x32_bf16: lane holds k = ks*32 + (lane>>4)*8 + i,
// n = ntile*16 + (lane&15).  Flat index: ((ks*4+nt)*64 + lane)*8 + i.
// ---------------------------------------------------------------------------
__global__ void prep_wrb(const float* __restrict__ W, const float* __restrict__ bias,
                         ushort* __restrict__ WrB) {
    const int ks   = blockIdx.x;          // 0..16
    const int nt   = threadIdx.x >> 6;    // 0..3
    const int lane = threadIdx.x & 63;
    const int g    = lane >> 4;
    const int n    = nt * 16 + (lane & 15);
    ushort* dst = WrB + (((size_t)ks * 4 + nt) * 64 + lane) * 8;
    #pragma unroll
    for (int i = 0; i < 8; ++i) {
        const int k = ks * 32 + g * 8 + i;
        float v;
        if (k < 512)      v = W[(size_t)(k >> 4) * 1024 + n * 16 + (k & 15)];
        else if (k < 528) v = bias[n * 16 + (k - 512)];
        else              v = 0.0f;
        __hip_bfloat16 hb = __float2bfloat16(v);
        dst[i] = *reinterpret_cast<ushort*>(&hb);
    }
}

// ---------------------------------------------------------------------------
// Main: 64 edges/block, 4 waves; wave w owns 16 edge-rows, all 64 m-cols.
// A-frag built in registers from ef (scalar) x neigh (8-vec); B-frag from
// prepacked global (L2-resident). C layout: col(m)=lane&15, row(e)=(lane>>4)*4+reg.
// ---------------------------------------------------------------------------
__global__ __launch_bounds__(256, 4) void msg_mfma(
    const float* __restrict__ ef,      // [E,32]
    const int*   __restrict__ src,     // [E]
    const int*   __restrict__ tgt,     // [E]
    const float* __restrict__ hidden,  // [N,16]
    const ushort* __restrict__ WrB,    // prepacked B fragments
    float*       __restrict__ out)     // [N,64]
{
    __shared__ float ef_s[64][36];     // cols 0..31 = ef, 32 = 1.0 (bias row), 33 = 0.0 (pad)
    __shared__ float neigh_s[64][20];  // gathered hidden rows (padded for float4 align)
    __shared__ int   tgt_s[64];

    const int tid = threadIdx.x;
    const int e0  = blockIdx.x * 64;

    // gather neighbor hidden: thread t -> edge t>>2, 4 floats
    {
        const int e  = tid >> 2;
        const int h4 = (tid & 3) * 4;
        const int s  = src[e0 + e];
        *(float4*)&neigh_s[e][h4] = *(const float4*)(hidden + (size_t)s * HIDDEN + h4);
    }
    // edge features: thread t -> edge t>>2, 8 floats
    {
        const int e  = tid >> 2;
        const int f8 = (tid & 3) * 8;
        const float* p = ef + (size_t)(e0 + e) * EDGE_FEAT + f8;
        *(float4*)&ef_s[e][f8]     = *(const float4*)(p);
        *(float4*)&ef_s[e][f8 + 4] = *(const float4*)(p + 4);
    }
    if (tid < 64) {
        ef_s[tid][32] = 1.0f;    // bias pseudo-feature
        ef_s[tid][33] = 0.0f;    // zero pad feature
        tgt_s[tid] = tgt[e0 + tid];
    }
    __syncthreads();

    const int wave  = tid >> 6;
    const int lane  = tid & 63;
    const int er    = lane & 15;       // edge-row within wave tile / also m-col in C
    const int g     = lane >> 4;       // k-group
    const int e_loc = wave * 16 + er;
    const int h0    = (g & 1) * 8;     // which half of hidden this lane's k-chunk covers
    const int fg    = g >> 1;          // f = 2*ks + fg

    // neighbor hidden half, held in registers for the whole K loop
    float nb[8];
    #pragma unroll
    for (int j = 0; j < 8; ++j) nb[j] = neigh_s[e_loc][h0 + j];

    f32x4 acc0 = {0.f,0.f,0.f,0.f}, acc1 = acc0, acc2 = acc0, acc3 = acc0;
    const bf16x8* Bp = (const bf16x8*)WrB;

    #pragma unroll
    for (int ks = 0; ks < KSTEPS; ++ks) {
        const float a = ef_s[e_loc][2 * ks + fg];
        bf16x8 af;
        #pragma unroll
        for (int j = 0; j < 8; ++j) {
            const float p = a * nb[j];
            __hip_bfloat16 hb = __float2bfloat16(p);
            af[j] = *reinterpret_cast<const short*>(&hb);
        }
        const bf16x8 b0 = Bp[(ks * 4 + 0) * 64 + lane];
        const bf16x8 b1 = Bp[(ks * 4 + 1) * 64 + lane];
        const bf16x8 b2 = Bp[(ks * 4 + 2) * 64 + lane];
        const bf16x8 b3 = Bp[(ks * 4 + 3) * 64 + lane];
        acc0 = __builtin_amdgcn_mfma_f32_16x16x32_bf16(af, b0, acc0, 0, 0, 0);
        acc1 = __builtin_amdgcn_mfma_f32_16x16x32_bf16(af, b1, acc1, 0, 0, 0);
        acc2 = __builtin_amdgcn_mfma_f32_16x16x32_bf16(af, b2, acc2, 0, 0, 0);
        acc3 = __builtin_amdgcn_mfma_f32_16x16x32_bf16(af, b3, acc3, 0, 0, 0);
    }

    // epilogue: C row = (lane>>4)*4 + reg -> edge; col = er -> m within n-tile.
    // Each atomic instruction covers 4 targets x 16 consecutive m = 4 aligned 64B lines.
    #pragma unroll
    for (int r = 0; r < 4; ++r) {
        const int t = tgt_s[wave * 16 + g * 4 + r];
        float* op = out + (size_t)t * MSG;
        atomicAdd(op + 0 * 16 + er, acc0[r]);
        atomicAdd(op + 16 + er, acc1[r]);
        atomicAdd(op + 32 + er, acc2[r]);
        atomicAdd(op + 48 + er, acc3[r]);
    }
}

extern "C" void kernel_launch(void* const* d_in, const int* in_sizes, int n_in,
                              void* d_out, int out_size, void* d_ws, size_t ws_size,
                              hipStream_t stream) {
    // inputs: 0 node_features (unused), 1 edge_features, 2 edge_sources,
    //         3 edge_targets, 4 hidden, 5 initial (unused), 6 W, 7 b
    const float* ef     = (const float*)d_in[1];
    const int*   src    = (const int*)d_in[2];
    const int*   tgt    = (const int*)d_in[3];
    const float* hidden = (const float*)d_in[4];
    const float* W      = (const float*)d_in[6];
    const float* bias   = (const float*)d_in[7];
    float*  out = (float*)d_out;
    ushort* WrB = (ushort*)d_ws;   // 17*4*64*8 bf16 = 69632 bytes

    hipMemsetAsync(out, 0, (size_t)out_size * sizeof(float), stream);
    prep_wrb<<<KSTEPS, 256, 0, stream>>>(W, bias, WrB);
    msg_mfma<<<N_EDGES / 64, 256, 0, stream>>>(ef, src, tgt, hidden, WrB, out);
}